// Round 11
// baseline (381.881 us; speedup 1.0000x reference)
//
#include <hip/hip_runtime.h>
#include <hip/hip_bf16.h>

#define F 256
#define V 512
#define NB 8   // texture batch
#define NC 8   // n_code
#define NH 4
#define DQ 64
#define EPS 1e-6f
#define CEXPQ 0.18033688f   // 0.125 * log2(e), folded into Q at qkv epilogue

typedef __hip_bfloat16 bf16;
typedef __attribute__((ext_vector_type(8))) short short8;   // 8 bf16 MFMA operand
typedef __attribute__((ext_vector_type(4))) float f32x4;    // MFMA accumulator
typedef __attribute__((ext_vector_type(4))) unsigned uint4v;

__device__ __forceinline__ float b2f(bf16 x){ return __bfloat162float(x); }
__device__ __forceinline__ float shf(short s){
    return __bfloat162float(__builtin_bit_cast(bf16, (unsigned short)s));
}

#define MFMA(a,b,c) __builtin_amdgcn_mfma_f32_16x16x32_bf16((a),(b),(c),0,0,0)

__device__ __forceinline__ unsigned pack2bf(float a, float b){
    unsigned short ua = __builtin_bit_cast(unsigned short, __float2bfloat16(a));
    unsigned short ub = __builtin_bit_cast(unsigned short, __float2bfloat16(b));
    return (unsigned)ua | ((unsigned)ub << 16);
}

// ---- K0: fused weight-cast (6x 256x256 fp32 -> bf16) + LayerNorm (frozen).
__global__ __launch_bounds__(256) void pre_kernel(const float* __restrict__ code,
                          const float* __restrict__ tex,
                          const float* __restrict__ ln1_g, const float* __restrict__ ln1_b,
                          const float* __restrict__ ln2_g, const float* __restrict__ ln2_b,
                          const float* __restrict__ w0, const float* __restrict__ w1,
                          const float* __restrict__ w2, const float* __restrict__ w3,
                          const float* __restrict__ w4, const float* __restrict__ w5,
                          bf16* __restrict__ cn, bf16* __restrict__ tn, bf16* __restrict__ tb,
                          bf16* __restrict__ wdst){
    if (blockIdx.x >= 2048){
        int bid = blockIdx.x - 2048;
        int which = bid >> 6;
        int idx = (((bid & 63) << 8) | threadIdx.x) << 2;
        const float* s = which==0?w0: which==1?w1: which==2?w2: which==3?w3: which==4?w4: w5;
        float4 v = *(const float4*)(s + idx);
        uint2 p; p.x = pack2bf(v.x, v.y); p.y = pack2bf(v.z, v.w);
        *(uint2*)(wdst + which * (F*F) + idx) = p;
        return;
    }
    int w = threadIdx.x >> 6, lane = threadIdx.x & 63;
    int r = blockIdx.x * 4 + w;
    int is_tex = r >> 12;
    int row = r & 4095;
    const float* src = is_tex ? tex : code;
    const float* g   = is_tex ? ln2_g : ln1_g;
    const float* be  = is_tex ? ln2_b : ln1_b;
    bf16* dst        = is_tex ? tn : cn;

    float4 x = *(const float4*)(src + row * F + lane * 4);
    if (is_tex){
        uint2 p; p.x = pack2bf(x.x, x.y); p.y = pack2bf(x.z, x.w);
        *(uint2*)(tb + row * F + lane * 4) = p;
    }
    float s = x.x + x.y + x.z + x.w;
    #pragma unroll
    for(int m = 1; m < 64; m <<= 1) s += __shfl_xor(s, m);
    float mu = s * (1.0f / F);
    float d0 = x.x - mu, d1 = x.y - mu, d2 = x.z - mu, d3 = x.w - mu;
    float q = d0*d0 + d1*d1 + d2*d2 + d3*d3;
    #pragma unroll
    for(int m = 1; m < 64; m <<= 1) q += __shfl_xor(q, m);
    float rs = rsqrtf(q * (1.0f / F) + EPS);
    float4 gg = *(const float4*)(g + lane * 4);
    float4 bb = *(const float4*)(be + lane * 4);
    uint2 p;
    p.x = pack2bf(d0 * rs * gg.x + bb.x, d1 * rs * gg.y + bb.y);
    p.y = pack2bf(d2 * rs * gg.z + bb.z, d3 * rs * gg.w + bb.w);
    *(uint2*)(dst + row * F + lane * 4) = p;
}

// ---- K1: QKV MFMA GEMM, M=4096 N=256 K=256. grid (64, 4, 3), 4 waves of 16x64. (frozen)
// z=0: Q (pre-scaled by CEXPQ) -> qn row-major; z=1: K -> k4 sigma-permuted A-frag layout
//   sigma(kt*16+i) = (i>>2)*8 + kt*4 + (i&3): QK^T output is lane-local PV B-frag.
// z=2: V -> v4 chunk-tiled.
__global__ __launch_bounds__(256)
void qkv_kernel(const bf16* __restrict__ cn,
                const bf16* __restrict__ tn,
                const bf16* __restrict__ wbf,
                const float* __restrict__ bq,
                const float* __restrict__ bk,
                const float* __restrict__ bv,
                bf16* __restrict__ qn,
                bf16* __restrict__ k4,
                bf16* __restrict__ v4){
    __shared__ bf16 ts[64][72];
    int which = blockIdx.z;
    const bf16* in   = (which == 0) ? tn : cn;
    const bf16* wb   = wbf + which * (F * F);
    const float* bias = (which == 0) ? bq : (which == 1) ? bk : bv;

    int tid = threadIdx.x;
    int w = tid >> 6, lane = tid & 63;
    int lg = lane >> 4, li = lane & 15;
    int rowbase = blockIdx.x * 64 + w * 16;
    int colbase = blockIdx.y * 64;

    f32x4 acc[4];
    #pragma unroll
    for(int ni = 0; ni < 4; ni++) acc[ni] = (f32x4){0.f,0.f,0.f,0.f};

    const bf16* arow = in + (rowbase + li) * F + lg * 8;
    const bf16* brow = wb + (colbase + li) * F + lg * 8;

    #pragma unroll
    for(int kc = 0; kc < 8; kc++){
        short8 a = *(const short8*)(arow + kc * 32);
        #pragma unroll
        for(int ni = 0; ni < 4; ni++){
            short8 bbf = *(const short8*)(brow + ni * 16 * F + kc * 32);
            acc[ni] = MFMA(a, bbf, acc[ni]);
        }
    }

    // stage (acc + bias) [* CEXPQ for Q] to LDS; V transposed [col][key_local]
    float cscale = (which == 0) ? CEXPQ : 1.0f;
    if (which < 2){
        #pragma unroll
        for(int ni = 0; ni < 4; ni++)
            #pragma unroll
            for(int r = 0; r < 4; r++)
                ts[w * 16 + lg * 4 + r][ni * 16 + li] =
                    __float2bfloat16((acc[ni][r] + bias[colbase + ni * 16 + li]) * cscale);
    } else {
        #pragma unroll
        for(int ni = 0; ni < 4; ni++)
            #pragma unroll
            for(int r = 0; r < 4; r++)
                ts[ni * 16 + li][w * 16 + lg * 4 + r] =
                    __float2bfloat16(acc[ni][r] + bias[colbase + ni * 16 + li]);
    }
    __syncthreads();

    if (which == 0){
        int rr = tid >> 2, gg2 = tid & 3;
        *(short8*)(qn + (blockIdx.x * 64 + rr) * F + colbase + gg2 * 16)
            = *(const short8*)&ts[rr][gg2 * 16];
    } else if (which == 1){
        // k4 fragment layout: fi = ((n*16+kc2)*2+kt)*8 + hh*2 + ks ; elem lgp*128+lip*8+j
        // sigma: frag (kt), A-row slot lip holds key (lip>>2)*8 + kt*4 + (lip&3)
        int n = blockIdx.x >> 3;
        int kc2base = (blockIdx.x & 7) * 2;
        int hh = blockIdx.y;
        #pragma unroll
        for(int rep = 0; rep < 2; rep++){
            int c = tid + 256 * rep;
            int f = c >> 6, wf = c & 63;
            int lgp = wf >> 4, lip = wf & 15;
            int kc2l = f >> 2, kt = (f >> 1) & 1, ks = f & 1;
            int keysel = ((lip >> 2) * 8) + kt * 4 + (lip & 3);
            int fi = ((n * 16 + kc2base + kc2l) * 2 + kt) * 8 + hh * 2 + ks;
            *(short8*)(k4 + fi * 512 + lgp * 128 + lip * 8)
                = *(const short8*)&ts[kc2l * 32 + keysel][ks * 32 + lgp * 8];
        }
    } else {
        int col = tid & 63, half = tid >> 6;
        int keybase = blockIdx.x * 64;
        int n = keybase >> 9;
        int keyl = (keybase & (V - 1)) + half * 16;
        int chunk = keyl >> 5, off = keyl & 31;
        *(short8*)(v4 + ((n * 16 + chunk) * F + colbase + col) * 32 + off)
            = *(const short8*)&ts[col][half * 16];
    }
}

// ---- K2 MEGA: flash attention + Wo + tex residual + ffln LN + W1/ReLU + W2 + residual -> out.
// grid (64, 8): x = (n = x&7 XCD swizzle, b = x>>3), y = 64-row qtile. NEW: 1024 thr =
// 16 waves = (4 heads x 2 q-halves x 2 kc-halves). Each wave runs R8's free-running flash
// body over its 8 chunks (no barriers in the loop); block count / K-V traffic / weight
// traffic all unchanged, but 2 blocks x 16 waves = 32 waves/CU (2x R8's residency).
// Partial (o,l) are exactly additive (no max-subtraction): c=1 -> c=0 reduce via an 18KB
// f32 LDS buffer placed after xs, 8 one-time barriers. MLP: 16 waves x 16-col tiles.
__global__ __launch_bounds__(1024, 8) void attn_mlp_kernel(const bf16* __restrict__ qn,
                                                           const bf16* __restrict__ k4,
                                                           const bf16* __restrict__ v4,
                                                           const bf16* __restrict__ wbf,
                                                           const float* __restrict__ bo,
                                                           const bf16* __restrict__ tb,
                                                           const float* __restrict__ ffg,
                                                           const float* __restrict__ ffb,
                                                           const float* __restrict__ b1,
                                                           const float* __restrict__ b2,
                                                           float* __restrict__ out){
    __shared__ __align__(16) char smem[33792 + 18432];
    bf16 (*xs)[264] = (bf16(*)[264])smem;                     // [64][264] ctx->x->xhat->h1
    float (*rb)[64][9] = (float(*)[64][9])(smem + 33792);     // [8 pairs][64 lanes][9]

    int n = blockIdx.x & 7, b = blockIdx.x >> 3, qt = blockIdx.y;
    int tid = threadIdx.x;
    int w = tid >> 6, lane = tid & 63;
    int h = w & 3, qh = (w >> 2) & 1, c = w >> 3;   // head, q-half, kc-half
    int lg = lane >> 4, li = lane & 15;

    // Q B-frags resident: 2 q-tiles of 16 (rows qt*64 + qh*32 + qq*16 + li)
    short8 qB[2][2];
    #pragma unroll
    for(int qq = 0; qq < 2; qq++)
        #pragma unroll
        for(int ks = 0; ks < 2; ks++)
            qB[qq][ks] = *(const short8*)(qn + (b * V + qt * 64 + qh * 32 + qq * 16 + li) * F
                                             + h * DQ + ks * 32 + lg * 8);

    f32x4 o[2][4], ls[2];
    #pragma unroll
    for(int qq = 0; qq < 2; qq++){
        #pragma unroll
        for(int dt = 0; dt < 4; dt++) o[qq][dt] = (f32x4){0.f,0.f,0.f,0.f};
        ls[qq] = (f32x4){0.f,0.f,0.f,0.f};
    }

    short8 ones8;
    #pragma unroll
    for(int j = 0; j < 8; j++) ones8[j] = (short)0x3F80;   // bf16 1.0

    int fel = lg * 128 + li * 8;

    #pragma unroll
    for(int i = 0; i < 8; i++){
        int kc = c * 8 + i;
        int fb = ((n * 16 + kc) * 2) * 8 + h * 2;
        short8 kA0 = *(const short8*)(k4 + (fb + 0) * 512 + fel);
        short8 kA1 = *(const short8*)(k4 + (fb + 1) * 512 + fel);
        short8 kA2 = *(const short8*)(k4 + (fb + 8) * 512 + fel);
        short8 kA3 = *(const short8*)(k4 + (fb + 9) * 512 + fel);
        const bf16* vb = v4 + ((n * 16 + kc) * F + h * DQ) * 32;
        short8 vA0 = *(const short8*)(vb + (0 * 16 + li) * 32 + lg * 8);
        short8 vA1 = *(const short8*)(vb + (1 * 16 + li) * 32 + lg * 8);
        short8 vA2 = *(const short8*)(vb + (2 * 16 + li) * 32 + lg * 8);
        short8 vA3 = *(const short8*)(vb + (3 * 16 + li) * 32 + lg * 8);

        #pragma unroll
        for(int qq = 0; qq < 2; qq++){
            f32x4 st0 = (f32x4){0.f,0.f,0.f,0.f};
            f32x4 st1 = (f32x4){0.f,0.f,0.f,0.f};
            __builtin_amdgcn_s_setprio(1);
            st0 = MFMA(kA0, qB[qq][0], st0);
            st1 = MFMA(kA2, qB[qq][0], st1);
            st0 = MFMA(kA1, qB[qq][1], st0);
            st1 = MFMA(kA3, qB[qq][1], st1);
            __builtin_amdgcn_s_setprio(0);

            // Q pre-scaled: p = exp2(st). sigma rows: st0[r]=P[key lg*8+r], st1[r]=P[key lg*8+4+r]
            float p0[4], p1[4];
            #pragma unroll
            for(int r = 0; r < 4; r++){
                p0[r] = exp2f(st0[r]);
                p1[r] = exp2f(st1[r]);
            }

            uint4v uv;
            uv.x = pack2bf(p0[0], p0[1]);
            uv.y = pack2bf(p0[2], p0[3]);
            uv.z = pack2bf(p1[0], p1[1]);
            uv.w = pack2bf(p1[2], p1[3]);
            short8 pfrag = __builtin_bit_cast(short8, uv);

            __builtin_amdgcn_s_setprio(1);
            o[qq][0] = MFMA(vA0, pfrag, o[qq][0]);
            o[qq][1] = MFMA(vA1, pfrag, o[qq][1]);
            o[qq][2] = MFMA(vA2, pfrag, o[qq][2]);
            o[qq][3] = MFMA(vA3, pfrag, o[qq][3]);
            ls[qq] = MFMA(ones8, pfrag, ls[qq]);   // partial l = sum_k P, lane-complete
            __builtin_amdgcn_s_setprio(0);
        }
    }

    // pairwise (c=1 -> c=0) additive reduction of (o, l), then ctx staging into xs.
    // rb pass granularity: (qq, half) -> 8 floats of o + l once. 8 one-time barriers.
    {
        int p = h * 2 + qh;
        float inv[2] = {0.f, 0.f};
        #pragma unroll
        for(int qq = 0; qq < 2; qq++){
            #pragma unroll
            for(int half = 0; half < 2; half++){
                if (c == 1){
                    #pragma unroll
                    for(int dd = 0; dd < 2; dd++)
                        #pragma unroll
                        for(int r = 0; r < 4; r++)
                            rb[p][lane][dd * 4 + r] = o[qq][half * 2 + dd][r];
                    if (half == 0) rb[p][lane][8] = ls[qq][0];
                }
                __syncthreads();
                if (c == 0){
                    if (half == 0) inv[qq] = 1.0f / (ls[qq][0] + rb[p][lane][8]);
                    #pragma unroll
                    for(int dd = 0; dd < 2; dd++){
                        int dt = half * 2 + dd;
                        float o0 = (o[qq][dt][0] + rb[p][lane][dd * 4 + 0]) * inv[qq];
                        float o1 = (o[qq][dt][1] + rb[p][lane][dd * 4 + 1]) * inv[qq];
                        float o2 = (o[qq][dt][2] + rb[p][lane][dd * 4 + 2]) * inv[qq];
                        float o3 = (o[qq][dt][3] + rb[p][lane][dd * 4 + 3]) * inv[qq];
                        uint2 pkd;
                        pkd.x = pack2bf(o0, o1);
                        pkd.y = pack2bf(o2, o3);
                        *(uint2*)&xs[qh * 32 + qq * 16 + li][h * DQ + dt * 16 + lg * 4] = pkd;
                    }
                }
                __syncthreads();
            }
        }
    }
    // xs now holds ctx for all 64 rows (last barrier above synchronizes)

    // ---- Wo GEMM + bo + tex residual -> xres (registers, fp32). 64 rows x 16 wave-cols.
    const bf16* Wo = wbf + 3 * (F * F);
    int colbase = w * 16;
    int col = colbase + li;
    f32x4 xac[4];
    #pragma unroll
    for(int mi = 0; mi < 4; mi++) xac[mi] = (f32x4){0.f,0.f,0.f,0.f};
    #pragma unroll
    for(int kc = 0; kc < 8; kc++){
        short8 bw = *(const short8*)(Wo + col * F + kc * 32 + lg * 8);
        #pragma unroll
        for(int mi = 0; mi < 4; mi++){
            short8 a = *(const short8*)&xs[mi * 16 + li][kc * 32 + lg * 8];
            xac[mi] = MFMA(a, bw, xac[mi]);
        }
    }
    float xres[4][4];
    #pragma unroll
    for(int mi = 0; mi < 4; mi++)
        #pragma unroll
        for(int r = 0; r < 4; r++){
            int qrel = mi * 16 + lg * 4 + r;
            xres[mi][r] = xac[mi][r] + bo[col]
                        + b2f(tb[(b * V + qt * 64 + qrel) * F + col]);
        }
    __syncthreads();                  // all ctx reads done
    // write x (bf16) into xs
    #pragma unroll
    for(int mi = 0; mi < 4; mi++)
        #pragma unroll
        for(int r = 0; r < 4; r++){
            int qrel = mi * 16 + lg * 4 + r;
            xs[qrel][col] = __float2bfloat16(xres[mi][r]);
        }
    __syncthreads();

    // ---- ffln LN: 16 threads per row (64 rows), one-pass, 16-lane shuffle reduce
    int row = tid >> 4, sub = tid & 15;
    short8 xa = *(const short8*)&xs[row][sub * 16];
    short8 xb2 = *(const short8*)&xs[row][sub * 16 + 8];
    float sum = 0.f, sq = 0.f;
    #pragma unroll
    for(int j = 0; j < 8; j++){
        float v0 = shf(xa[j]), v1 = shf(xb2[j]);
        sum += v0 + v1; sq += v0 * v0 + v1 * v1;
    }
    #pragma unroll
    for(int m = 1; m < 16; m <<= 1){
        sum += __shfl_xor(sum, m);
        sq  += __shfl_xor(sq, m);
    }
    float mu = sum * (1.0f / F);
    float var = sq * (1.0f / F) - mu * mu;
    float rsv = rsqrtf(var + EPS);
    {
        int c0 = sub * 16;
        float4 g0 = *(const float4*)(ffg + c0);
        float4 g1 = *(const float4*)(ffg + c0 + 4);
        float4 g2 = *(const float4*)(ffg + c0 + 8);
        float4 g3 = *(const float4*)(ffg + c0 + 12);
        float4 f0 = *(const float4*)(ffb + c0);
        float4 f1 = *(const float4*)(ffb + c0 + 4);
        float4 f2 = *(const float4*)(ffb + c0 + 8);
        float4 f3 = *(const float4*)(ffb + c0 + 12);
        float n0 = (shf(xa[0]) - mu) * rsv * g0.x + f0.x;
        float n1 = (shf(xa[1]) - mu) * rsv * g0.y + f0.y;
        float n2 = (shf(xa[2]) - mu) * rsv * g0.z + f0.z;
        float n3 = (shf(xa[3]) - mu) * rsv * g0.w + f0.w;
        float n4 = (shf(xa[4]) - mu) * rsv * g1.x + f1.x;
        float n5 = (shf(xa[5]) - mu) * rsv * g1.y + f1.y;
        float n6 = (shf(xa[6]) - mu) * rsv * g1.z + f1.z;
        float n7 = (shf(xa[7]) - mu) * rsv * g1.w + f1.w;
        float m0 = (shf(xb2[0]) - mu) * rsv * g2.x + f2.x;
        float m1 = (shf(xb2[1]) - mu) * rsv * g2.y + f2.y;
        float m2 = (shf(xb2[2]) - mu) * rsv * g2.z + f2.z;
        float m3 = (shf(xb2[3]) - mu) * rsv * g2.w + f2.w;
        float m4 = (shf(xb2[4]) - mu) * rsv * g3.x + f3.x;
        float m5 = (shf(xb2[5]) - mu) * rsv * g3.y + f3.y;
        float m6 = (shf(xb2[6]) - mu) * rsv * g3.z + f3.z;
        float m7 = (shf(xb2[7]) - mu) * rsv * g3.w + f3.w;
        uint4v pa, pb;
        pa.x = pack2bf(n0, n1); pa.y = pack2bf(n2, n3);
        pa.z = pack2bf(n4, n5); pa.w = pack2bf(n6, n7);
        pb.x = pack2bf(m0, m1); pb.y = pack2bf(m2, m3);
        pb.z = pack2bf(m4, m5); pb.w = pack2bf(m6, m7);
        *(short8*)&xs[row][sub * 16]     = __builtin_bit_cast(short8, pa);
        *(short8*)&xs[row][sub * 16 + 8] = __builtin_bit_cast(short8, pb);
    }
    __syncthreads();

    // ---- GEMM1: h = relu(xhat @ W1^T + b1), 64 rows x 16 wave-cols
    const bf16* W1b = wbf + 4 * (F * F);
    f32x4 hac[4];
    #pragma unroll
    for(int mi = 0; mi < 4; mi++) hac[mi] = (f32x4){0.f,0.f,0.f,0.f};
    #pragma unroll
    for(int kc = 0; kc < 8; kc++){
        short8 bw = *(const short8*)(W1b + col * F + kc * 32 + lg * 8);
        #pragma unroll
        for(int mi = 0; mi < 4; mi++){
            short8 a = *(const short8*)&xs[mi * 16 + li][kc * 32 + lg * 8];
            hac[mi] = MFMA(a, bw, hac[mi]);
        }
    }
    __syncthreads();                  // xhat reads done
    #pragma unroll
    for(int mi = 0; mi < 4; mi++)
        #pragma unroll
        for(int r = 0; r < 4; r++){
            int rr = mi * 16 + lg * 4 + r;
            xs[rr][col] = __float2bfloat16(fmaxf(hac[mi][r] + b1[col], 0.f));
        }
    __syncthreads();

    // ---- GEMM2: out = x + h @ W2^T + b2
    const bf16* W2b = wbf + 5 * (F * F);
    f32x4 oac[4];
    #pragma unroll
    for(int mi = 0; mi < 4; mi++) oac[mi] = (f32x4){0.f,0.f,0.f,0.f};
    #pragma unroll
    for(int kc = 0; kc < 8; kc++){
        short8 bw = *(const short8*)(W2b + col * F + kc * 32 + lg * 8);
        #pragma unroll
        for(int mi = 0; mi < 4; mi++){
            short8 a = *(const short8*)&xs[mi * 16 + li][kc * 32 + lg * 8];
            oac[mi] = MFMA(a, bw, oac[mi]);
        }
    }
    #pragma unroll
    for(int mi = 0; mi < 4; mi++)
        #pragma unroll
        for(int r = 0; r < 4; r++){
            int qrel = mi * 16 + lg * 4 + r;
            int ro = (b * NC + n) * V + qt * 64 + qrel;
            out[ro * F + col] = oac[mi][r] + b2[col] + xres[mi][r];
        }
}

extern "C" void kernel_launch(void* const* d_in, const int* in_sizes, int n_in,
                              void* d_out, int out_size, void* d_ws, size_t ws_size,
                              hipStream_t stream) {
    const float* code_map = (const float*)d_in[0];
    const float* tex_map  = (const float*)d_in[1];
    const float* Wq = (const float*)d_in[2];  const float* bq = (const float*)d_in[3];
    const float* Wk = (const float*)d_in[4];  const float* bk = (const float*)d_in[5];
    const float* Wv = (const float*)d_in[6];  const float* bv = (const float*)d_in[7];
    const float* Wo = (const float*)d_in[8];  const float* bo = (const float*)d_in[9];
    const float* ln1_g = (const float*)d_in[10]; const float* ln1_b = (const float*)d_in[11];
    const float* ln2_g = (const float*)d_in[12]; const float* ln2_b = (const float*)d_in[13];
    const float* ffln_g = (const float*)d_in[14]; const float* ffln_b = (const float*)d_in[15];
    const float* W1 = (const float*)d_in[16]; const float* b1 = (const float*)d_in[17];
    const float* W2 = (const float*)d_in[18]; const float* b2 = (const float*)d_in[19];
    float* out = (float*)d_out;

    // ws layout (bf16 elements)
    bf16* ws  = (bf16*)d_ws;
    bf16* qn  = ws;                       // 4096*256 = 1048576 (pre-scaled Q)
    bf16* k4  = qn + 1048576;             // 1048576 (A-frag layout, sigma-permuted keys)
    bf16* v4  = k4 + 1048576;             // 1048576 (chunk-tiled V)
    bf16* cn  = v4 + 1048576;             // 1048576
    bf16* tn  = cn + 1048576;             // 1048576
    bf16* tb  = tn + 1048576;             // 1048576 (bf16 texture copy)
    bf16* wbf = tb + 1048576;             // 6*256*256 = 393216 (Wq,Wk,Wv,Wo,W1,W2)

    pre_kernel<<<2048 + 384, 256, 0, stream>>>(code_map, tex_map, ln1_g, ln1_b, ln2_g, ln2_b,
                                               Wq, Wk, Wv, Wo, W1, W2, cn, tn, tb, wbf);
    qkv_kernel<<<dim3(64, 4, 3), 256, 0, stream>>>(cn, tn, wbf, bq, bk, bv, qn, k4, v4);
    attn_mlp_kernel<<<dim3(64, 8), 1024, 0, stream>>>(qn, k4, v4, wbf, bo, tb,
                                                      ffln_g, ffln_b, b1, b2, out);
}

// Round 12
// 182.081 us; speedup vs baseline: 2.0973x; 2.0973x over previous
//
#include <hip/hip_runtime.h>
#include <hip/hip_bf16.h>

#define F 256
#define V 512
#define NB 8   // texture batch
#define NC 8   // n_code
#define NH 4
#define DQ 64
#define EPS 1e-6f
#define CEXPQ 0.18033688f   // 0.125 * log2(e), folded into Q at qkv epilogue

typedef __hip_bfloat16 bf16;
typedef __attribute__((ext_vector_type(8))) short short8;   // 8 bf16 MFMA operand
typedef __attribute__((ext_vector_type(4))) float f32x4;    // MFMA accumulator
typedef __attribute__((ext_vector_type(4))) unsigned uint4v;

__device__ __forceinline__ float b2f(bf16 x){ return __bfloat162float(x); }
__device__ __forceinline__ float shf(short s){
    return __bfloat162float(__builtin_bit_cast(bf16, (unsigned short)s));
}

#define MFMA(a,b,c) __builtin_amdgcn_mfma_f32_16x16x32_bf16((a),(b),(c),0,0,0)

__device__ __forceinline__ unsigned pack2bf(float a, float b){
    unsigned short ua = __builtin_bit_cast(unsigned short, __float2bfloat16(a));
    unsigned short ub = __builtin_bit_cast(unsigned short, __float2bfloat16(b));
    return (unsigned)ua | ((unsigned)ub << 16);
}

// ---- K0: fused weight-cast (6x 256x256 fp32 -> bf16) + LayerNorm (R5-proven, frozen).
// blocks [0,2048): LN wave-per-row; blocks [2048,2432): castw.
__global__ __launch_bounds__(256) void pre_kernel(const float* __restrict__ code,
                          const float* __restrict__ tex,
                          const float* __restrict__ ln1_g, const float* __restrict__ ln1_b,
                          const float* __restrict__ ln2_g, const float* __restrict__ ln2_b,
                          const float* __restrict__ w0, const float* __restrict__ w1,
                          const float* __restrict__ w2, const float* __restrict__ w3,
                          const float* __restrict__ w4, const float* __restrict__ w5,
                          bf16* __restrict__ cn, bf16* __restrict__ tn, bf16* __restrict__ tb,
                          bf16* __restrict__ wdst){
    if (blockIdx.x >= 2048){
        int bid = blockIdx.x - 2048;
        int which = bid >> 6;
        int idx = (((bid & 63) << 8) | threadIdx.x) << 2;
        const float* s = which==0?w0: which==1?w1: which==2?w2: which==3?w3: which==4?w4: w5;
        float4 v = *(const float4*)(s + idx);
        uint2 p; p.x = pack2bf(v.x, v.y); p.y = pack2bf(v.z, v.w);
        *(uint2*)(wdst + which * (F*F) + idx) = p;
        return;
    }
    int w = threadIdx.x >> 6, lane = threadIdx.x & 63;
    int r = blockIdx.x * 4 + w;
    int is_tex = r >> 12;
    int row = r & 4095;
    const float* src = is_tex ? tex : code;
    const float* g   = is_tex ? ln2_g : ln1_g;
    const float* be  = is_tex ? ln2_b : ln1_b;
    bf16* dst        = is_tex ? tn : cn;

    float4 x = *(const float4*)(src + row * F + lane * 4);
    if (is_tex){
        uint2 p; p.x = pack2bf(x.x, x.y); p.y = pack2bf(x.z, x.w);
        *(uint2*)(tb + row * F + lane * 4) = p;
    }
    float s = x.x + x.y + x.z + x.w;
    #pragma unroll
    for(int m = 1; m < 64; m <<= 1) s += __shfl_xor(s, m);
    float mu = s * (1.0f / F);
    float d0 = x.x - mu, d1 = x.y - mu, d2 = x.z - mu, d3 = x.w - mu;
    float q = d0*d0 + d1*d1 + d2*d2 + d3*d3;
    #pragma unroll
    for(int m = 1; m < 64; m <<= 1) q += __shfl_xor(q, m);
    float rs = rsqrtf(q * (1.0f / F) + EPS);
    float4 gg = *(const float4*)(g + lane * 4);
    float4 bb = *(const float4*)(be + lane * 4);
    uint2 p;
    p.x = pack2bf(d0 * rs * gg.x + bb.x, d1 * rs * gg.y + bb.y);
    p.y = pack2bf(d2 * rs * gg.z + bb.z, d3 * rs * gg.w + bb.w);
    *(uint2*)(dst + row * F + lane * 4) = p;
}

// ---- K1: QKV MFMA GEMM, M=4096 N=256 K=256. grid (64, 4, 3), 4 waves of 16x64. (frozen)
// z=0: Q (pre-scaled by CEXPQ) -> qn row-major; z=1: K -> k4 sigma-permuted A-frag layout
//   sigma(kt*16+i) = (i>>2)*8 + kt*4 + (i&3): QK^T output is lane-local PV B-frag.
// z=2: V -> v4 chunk-tiled.
__global__ __launch_bounds__(256)
void qkv_kernel(const bf16* __restrict__ cn,
                const bf16* __restrict__ tn,
                const bf16* __restrict__ wbf,
                const float* __restrict__ bq,
                const float* __restrict__ bk,
                const float* __restrict__ bv,
                bf16* __restrict__ qn,
                bf16* __restrict__ k4,
                bf16* __restrict__ v4){
    __shared__ bf16 ts[64][72];
    int which = blockIdx.z;
    const bf16* in   = (which == 0) ? tn : cn;
    const bf16* wb   = wbf + which * (F * F);
    const float* bias = (which == 0) ? bq : (which == 1) ? bk : bv;

    int tid = threadIdx.x;
    int w = tid >> 6, lane = tid & 63;
    int lg = lane >> 4, li = lane & 15;
    int rowbase = blockIdx.x * 64 + w * 16;
    int colbase = blockIdx.y * 64;

    f32x4 acc[4];
    #pragma unroll
    for(int ni = 0; ni < 4; ni++) acc[ni] = (f32x4){0.f,0.f,0.f,0.f};

    const bf16* arow = in + (rowbase + li) * F + lg * 8;
    const bf16* brow = wb + (colbase + li) * F + lg * 8;

    #pragma unroll
    for(int kc = 0; kc < 8; kc++){
        short8 a = *(const short8*)(arow + kc * 32);
        #pragma unroll
        for(int ni = 0; ni < 4; ni++){
            short8 bbf = *(const short8*)(brow + ni * 16 * F + kc * 32);
            acc[ni] = MFMA(a, bbf, acc[ni]);
        }
    }

    // stage (acc + bias) [* CEXPQ for Q] to LDS; V transposed [col][key_local]
    float cscale = (which == 0) ? CEXPQ : 1.0f;
    if (which < 2){
        #pragma unroll
        for(int ni = 0; ni < 4; ni++)
            #pragma unroll
            for(int r = 0; r < 4; r++)
                ts[w * 16 + lg * 4 + r][ni * 16 + li] =
                    __float2bfloat16((acc[ni][r] + bias[colbase + ni * 16 + li]) * cscale);
    } else {
        #pragma unroll
        for(int ni = 0; ni < 4; ni++)
            #pragma unroll
            for(int r = 0; r < 4; r++)
                ts[ni * 16 + li][w * 16 + lg * 4 + r] =
                    __float2bfloat16(acc[ni][r] + bias[colbase + ni * 16 + li]);
    }
    __syncthreads();

    if (which == 0){
        int rr = tid >> 2, gg2 = tid & 3;
        *(short8*)(qn + (blockIdx.x * 64 + rr) * F + colbase + gg2 * 16)
            = *(const short8*)&ts[rr][gg2 * 16];
    } else if (which == 1){
        // k4 fragment layout: fi = ((n*16+kc2)*2+kt)*8 + hh*2 + ks ; elem lgp*128+lip*8+j
        // sigma: frag (kt), A-row slot lip holds key (lip>>2)*8 + kt*4 + (lip&3)
        int n = blockIdx.x >> 3;
        int kc2base = (blockIdx.x & 7) * 2;
        int hh = blockIdx.y;
        #pragma unroll
        for(int rep = 0; rep < 2; rep++){
            int c = tid + 256 * rep;
            int f = c >> 6, wf = c & 63;
            int lgp = wf >> 4, lip = wf & 15;
            int kc2l = f >> 2, kt = (f >> 1) & 1, ks = f & 1;
            int keysel = ((lip >> 2) * 8) + kt * 4 + (lip & 3);
            int fi = ((n * 16 + kc2base + kc2l) * 2 + kt) * 8 + hh * 2 + ks;
            *(short8*)(k4 + fi * 512 + lgp * 128 + lip * 8)
                = *(const short8*)&ts[kc2l * 32 + keysel][ks * 32 + lgp * 8];
        }
    } else {
        int col = tid & 63, half = tid >> 6;
        int keybase = blockIdx.x * 64;
        int n = keybase >> 9;
        int keyl = (keybase & (V - 1)) + half * 16;
        int chunk = keyl >> 5, off = keyl & 31;
        *(short8*)(v4 + ((n * 16 + chunk) * F + colbase + col) * 32 + off)
            = *(const short8*)&ts[col][half * 16];
    }
}

// ---- K2 MEGA (R8-proven best, 70.5us): flash attention + Wo + tex residual + ffln LN +
// W1/ReLU + W2 + residual -> out. grid (64, 8): x = (n = x&7 XCD swizzle, b = x>>3),
// y = 64-row qtile. 512 thr = 8 waves = (4 heads x 2 q-halves). Q pre-scaled (exp2 direct);
// l via ones-column MFMA (lane-complete); sigma-permuted k4 -> P lane-local for PV.
// Occupancy campaign verdict (R7/R10/R11): smaller blocks double weight traffic; 64KB LDS
// staging halves residency; 16-wave blocks starve VGPRs -> spills. This design point is
// the measured optimum: 64 VGPR, 33KB LDS, zero flash-loop barriers.
__global__ __launch_bounds__(512) void attn_mlp_kernel(const bf16* __restrict__ qn,
                                                       const bf16* __restrict__ k4,
                                                       const bf16* __restrict__ v4,
                                                       const bf16* __restrict__ wbf,
                                                       const float* __restrict__ bo,
                                                       const bf16* __restrict__ tb,
                                                       const float* __restrict__ ffg,
                                                       const float* __restrict__ ffb,
                                                       const float* __restrict__ b1,
                                                       const float* __restrict__ b2,
                                                       float* __restrict__ out){
    __shared__ bf16 xs[64][264];        // ctx -> x -> xhat -> h1 (reused)
    int n = blockIdx.x & 7, b = blockIdx.x >> 3, qt = blockIdx.y;
    int tid = threadIdx.x;
    int w = tid >> 6, lane = tid & 63;
    int h = w & 3, qh = w >> 2;
    int lg = lane >> 4, li = lane & 15;

    // Q B-frags resident: 2 q-tiles of 16
    short8 qB[2][2];
    #pragma unroll
    for(int qq = 0; qq < 2; qq++)
        #pragma unroll
        for(int ks = 0; ks < 2; ks++)
            qB[qq][ks] = *(const short8*)(qn + (b * V + qt * 64 + qh * 32 + qq * 16 + li) * F
                                             + h * DQ + ks * 32 + lg * 8);

    f32x4 o[2][4], ls[2];
    #pragma unroll
    for(int qq = 0; qq < 2; qq++){
        #pragma unroll
        for(int dt = 0; dt < 4; dt++) o[qq][dt] = (f32x4){0.f,0.f,0.f,0.f};
        ls[qq] = (f32x4){0.f,0.f,0.f,0.f};
    }

    short8 ones8;
    #pragma unroll
    for(int j = 0; j < 8; j++) ones8[j] = (short)0x3F80;   // bf16 1.0

    int fel = lg * 128 + li * 8;

    #pragma unroll
    for(int kc = 0; kc < 16; kc++){
        int fb = ((n * 16 + kc) * 2) * 8 + h * 2;
        short8 kA0 = *(const short8*)(k4 + (fb + 0) * 512 + fel);
        short8 kA1 = *(const short8*)(k4 + (fb + 1) * 512 + fel);
        short8 kA2 = *(const short8*)(k4 + (fb + 8) * 512 + fel);
        short8 kA3 = *(const short8*)(k4 + (fb + 9) * 512 + fel);
        const bf16* vb = v4 + ((n * 16 + kc) * F + h * DQ) * 32;
        short8 vA0 = *(const short8*)(vb + (0 * 16 + li) * 32 + lg * 8);
        short8 vA1 = *(const short8*)(vb + (1 * 16 + li) * 32 + lg * 8);
        short8 vA2 = *(const short8*)(vb + (2 * 16 + li) * 32 + lg * 8);
        short8 vA3 = *(const short8*)(vb + (3 * 16 + li) * 32 + lg * 8);

        #pragma unroll
        for(int qq = 0; qq < 2; qq++){
            f32x4 st0 = (f32x4){0.f,0.f,0.f,0.f};
            f32x4 st1 = (f32x4){0.f,0.f,0.f,0.f};
            __builtin_amdgcn_s_setprio(1);
            st0 = MFMA(kA0, qB[qq][0], st0);
            st1 = MFMA(kA2, qB[qq][0], st1);
            st0 = MFMA(kA1, qB[qq][1], st0);
            st1 = MFMA(kA3, qB[qq][1], st1);
            __builtin_amdgcn_s_setprio(0);

            // Q pre-scaled: p = exp2(st). sigma rows: st0[r]=P[key lg*8+r], st1[r]=P[key lg*8+4+r]
            float p0[4], p1[4];
            #pragma unroll
            for(int r = 0; r < 4; r++){
                p0[r] = exp2f(st0[r]);
                p1[r] = exp2f(st1[r]);
            }

            uint4v uv;
            uv.x = pack2bf(p0[0], p0[1]);
            uv.y = pack2bf(p0[2], p0[3]);
            uv.z = pack2bf(p1[0], p1[1]);
            uv.w = pack2bf(p1[2], p1[3]);
            short8 pfrag = __builtin_bit_cast(short8, uv);

            __builtin_amdgcn_s_setprio(1);
            o[qq][0] = MFMA(vA0, pfrag, o[qq][0]);
            o[qq][1] = MFMA(vA1, pfrag, o[qq][1]);
            o[qq][2] = MFMA(vA2, pfrag, o[qq][2]);
            o[qq][3] = MFMA(vA3, pfrag, o[qq][3]);
            ls[qq] = MFMA(ones8, pfrag, ls[qq]);   // l = sum_k P, lane-complete
            __builtin_amdgcn_s_setprio(0);
        }
    }

    float inv[2];
    #pragma unroll
    for(int qq = 0; qq < 2; qq++) inv[qq] = 1.0f / ls[qq][0];

    // stage normalized O to LDS as ctx[qrel][col]
    #pragma unroll
    for(int qq = 0; qq < 2; qq++)
        #pragma unroll
        for(int dt = 0; dt < 4; dt++){
            uint2 pkd;
            pkd.x = pack2bf(o[qq][dt][0] * inv[qq], o[qq][dt][1] * inv[qq]);
            pkd.y = pack2bf(o[qq][dt][2] * inv[qq], o[qq][dt][3] * inv[qq]);
            *(uint2*)&xs[qh * 32 + qq * 16 + li][h * DQ + dt * 16 + lg * 4] = pkd;
        }
    __syncthreads();

    // ---- Wo GEMM + bo + tex residual -> xres (registers, fp32). 64 rows x 32 wave-cols.
    const bf16* Wo = wbf + 3 * (F * F);
    int colbase = w * 32;
    f32x4 xac[4][2];
    #pragma unroll
    for(int mi = 0; mi < 4; mi++)
        #pragma unroll
        for(int ni = 0; ni < 2; ni++) xac[mi][ni] = (f32x4){0.f,0.f,0.f,0.f};
    #pragma unroll
    for(int kc = 0; kc < 8; kc++){
        short8 a[4];
        #pragma unroll
        for(int mi = 0; mi < 4; mi++)
            a[mi] = *(const short8*)&xs[mi * 16 + li][kc * 32 + lg * 8];
        #pragma unroll
        for(int ni = 0; ni < 2; ni++){
            short8 bw = *(const short8*)(Wo + (colbase + ni * 16 + li) * F + kc * 32 + lg * 8);
            #pragma unroll
            for(int mi = 0; mi < 4; mi++)
                xac[mi][ni] = MFMA(a[mi], bw, xac[mi][ni]);
        }
    }
    float xres[4][2][4];
    #pragma unroll
    for(int mi = 0; mi < 4; mi++)
        #pragma unroll
        for(int r = 0; r < 4; r++){
            int qrel = mi * 16 + lg * 4 + r;
            #pragma unroll
            for(int ni = 0; ni < 2; ni++){
                int col = colbase + ni * 16 + li;
                xres[mi][ni][r] = xac[mi][ni][r] + bo[col]
                                + b2f(tb[(b * V + qt * 64 + qrel) * F + col]);
            }
        }
    __syncthreads();                  // all ctx reads done
    // write x (bf16) into xs
    #pragma unroll
    for(int mi = 0; mi < 4; mi++)
        #pragma unroll
        for(int r = 0; r < 4; r++){
            int qrel = mi * 16 + lg * 4 + r;
            #pragma unroll
            for(int ni = 0; ni < 2; ni++)
                xs[qrel][colbase + ni * 16 + li] = __float2bfloat16(xres[mi][ni][r]);
        }
    __syncthreads();

    // ---- ffln LN: 8 threads per row (64 rows), one-pass, 8-lane shuffle reduce
    int row = tid >> 3, sub = tid & 7;
    short8 xv[4];
    #pragma unroll
    for(int seg = 0; seg < 4; seg++)
        xv[seg] = *(const short8*)&xs[row][sub * 32 + seg * 8];
    float sum = 0.f, sq = 0.f;
    #pragma unroll
    for(int seg = 0; seg < 4; seg++)
        #pragma unroll
        for(int j = 0; j < 8; j++){
            float v0 = shf(xv[seg][j]);
            sum += v0; sq += v0 * v0;
        }
    #pragma unroll
    for(int m = 1; m < 8; m <<= 1){
        sum += __shfl_xor(sum, m);
        sq  += __shfl_xor(sq, m);
    }
    float mu = sum * (1.0f / F);
    float var = sq * (1.0f / F) - mu * mu;
    float rsv = rsqrtf(var + EPS);
    #pragma unroll
    for(int seg = 0; seg < 4; seg++){
        int c = sub * 32 + seg * 8;
        float4 g0 = *(const float4*)(ffg + c);
        float4 g1 = *(const float4*)(ffg + c + 4);
        float4 f0 = *(const float4*)(ffb + c);
        float4 f1 = *(const float4*)(ffb + c + 4);
        float n0 = (shf(xv[seg][0]) - mu) * rsv * g0.x + f0.x;
        float n1 = (shf(xv[seg][1]) - mu) * rsv * g0.y + f0.y;
        float n2 = (shf(xv[seg][2]) - mu) * rsv * g0.z + f0.z;
        float n3 = (shf(xv[seg][3]) - mu) * rsv * g0.w + f0.w;
        float n4 = (shf(xv[seg][4]) - mu) * rsv * g1.x + f1.x;
        float n5 = (shf(xv[seg][5]) - mu) * rsv * g1.y + f1.y;
        float n6 = (shf(xv[seg][6]) - mu) * rsv * g1.z + f1.z;
        float n7 = (shf(xv[seg][7]) - mu) * rsv * g1.w + f1.w;
        uint4v pk;
        pk.x = pack2bf(n0, n1); pk.y = pack2bf(n2, n3);
        pk.z = pack2bf(n4, n5); pk.w = pack2bf(n6, n7);
        *(short8*)&xs[row][c] = __builtin_bit_cast(short8, pk);
    }
    __syncthreads();

    // ---- GEMM1: h = relu(xhat @ W1^T + b1), 64 rows x 32 wave-cols
    const bf16* W1b = wbf + 4 * (F * F);
    f32x4 hac[4][2];
    #pragma unroll
    for(int mi = 0; mi < 4; mi++)
        #pragma unroll
        for(int ni = 0; ni < 2; ni++) hac[mi][ni] = (f32x4){0.f,0.f,0.f,0.f};
    #pragma unroll
    for(int kc = 0; kc < 8; kc++){
        short8 a[4];
        #pragma unroll
        for(int mi = 0; mi < 4; mi++)
            a[mi] = *(const short8*)&xs[mi * 16 + li][kc * 32 + lg * 8];
        #pragma unroll
        for(int ni = 0; ni < 2; ni++){
            short8 bw = *(const short8*)(W1b + (colbase + ni * 16 + li) * F + kc * 32 + lg * 8);
            #pragma unroll
            for(int mi = 0; mi < 4; mi++)
                hac[mi][ni] = MFMA(a[mi], bw, hac[mi][ni]);
        }
    }
    __syncthreads();                  // xhat reads done
    #pragma unroll
    for(int mi = 0; mi < 4; mi++)
        #pragma unroll
        for(int r = 0; r < 4; r++){
            int rr = mi * 16 + lg * 4 + r;
            #pragma unroll
            for(int ni = 0; ni < 2; ni++){
                int col = colbase + ni * 16 + li;
                xs[rr][col] = __float2bfloat16(fmaxf(hac[mi][ni][r] + b1[col], 0.f));
            }
        }
    __syncthreads();

    // ---- GEMM2: out = x + h @ W2^T + b2
    const bf16* W2b = wbf + 5 * (F * F);
    f32x4 oac[4][2];
    #pragma unroll
    for(int mi = 0; mi < 4; mi++)
        #pragma unroll
        for(int ni = 0; ni < 2; ni++) oac[mi][ni] = (f32x4){0.f,0.f,0.f,0.f};
    #pragma unroll
    for(int kc = 0; kc < 8; kc++){
        short8 a[4];
        #pragma unroll
        for(int mi = 0; mi < 4; mi++)
            a[mi] = *(const short8*)&xs[mi * 16 + li][kc * 32 + lg * 8];
        #pragma unroll
        for(int ni = 0; ni < 2; ni++){
            short8 bw = *(const short8*)(W2b + (colbase + ni * 16 + li) * F + kc * 32 + lg * 8);
            #pragma unroll
            for(int mi = 0; mi < 4; mi++)
                oac[mi][ni] = MFMA(a[mi], bw, oac[mi][ni]);
        }
    }
    #pragma unroll
    for(int mi = 0; mi < 4; mi++)
        #pragma unroll
        for(int r = 0; r < 4; r++){
            int qrel = mi * 16 + lg * 4 + r;
            int ro = (b * NC + n) * V + qt * 64 + qrel;
            #pragma unroll
            for(int ni = 0; ni < 2; ni++){
                int col = colbase + ni * 16 + li;
                out[ro * F + col] = oac[mi][ni][r] + b2[col] + xres[mi][ni][r];
            }
        }
}

extern "C" void kernel_launch(void* const* d_in, const int* in_sizes, int n_in,
                              void* d_out, int out_size, void* d_ws, size_t ws_size,
                              hipStream_t stream) {
    const float* code_map = (const float*)d_in[0];
    const float* tex_map  = (const float*)d_in[1];
    const float* Wq = (const float*)d_in[2];  const float* bq = (const float*)d_in[3];
    const float* Wk = (const float*)d_in[4];  const float* bk = (const float*)d_in[5];
    const float* Wv = (const float*)d_in[6];  const float* bv = (const float*)d_in[7];
    const float* Wo = (const float*)d_in[8];  const float* bo = (const float*)d_in[9];
    const float* ln1_g = (const float*)d_in[10]; const float* ln1_b = (const float*)d_in[11];
    const float* ln2_g = (const float*)d_in[12]; const float* ln2_b = (const float*)d_in[13];
    const float* ffln_g = (const float*)d_in[14]; const float* ffln_b = (const float*)d_in[15];
    const float* W1 = (const float*)d_in[16]; const float* b1 = (const float*)d_in[17];
    const float* W2 = (const float*)d_in[18]; const float* b2 = (const float*)d_in[19];
    float* out = (float*)d_out;

    // ws layout (bf16 elements)
    bf16* ws  = (bf16*)d_ws;
    bf16* qn  = ws;                       // 4096*256 = 1048576 (pre-scaled Q)
    bf16* k4  = qn + 1048576;             // 1048576 (A-frag layout, sigma-permuted keys)
    bf16* v4  = k4 + 1048576;             // 1048576 (chunk-tiled V)
    bf16* cn  = v4 + 1048576;             // 1048576
    bf16* tn  = cn + 1048576;             // 1048576
    bf16* tb  = tn + 1048576;             // 1048576 (bf16 texture copy)
    bf16* wbf = tb + 1048576;             // 6*256*256 = 393216 (Wq,Wk,Wv,Wo,W1,W2)

    pre_kernel<<<2048 + 384, 256, 0, stream>>>(code_map, tex_map, ln1_g, ln1_b, ln2_g, ln2_b,
                                               Wq, Wk, Wv, Wo, W1, W2, cn, tn, tb, wbf);
    qkv_kernel<<<dim3(64, 4, 3), 256, 0, stream>>>(cn, tn, wbf, bq, bk, bv, qn, k4, v4);
    attn_mlp_kernel<<<dim3(64, 8), 512, 0, stream>>>(qn, k4, v4, wbf, bo, tb,
                                                     ffln_g, ffln_b, b1, b2, out);
}